// Round 2
// baseline (6772.280 us; speedup 1.0000x reference)
//
#include <hip/hip_runtime.h>

// ============================================================================
// ViT encoder (patch embed + windowed block + global block) on gfx950.
// Round 2: dtype-agnostic (runtime fp32-vs-bf16 detection) + round-1 pipeline.
//   - detect_k sniffs x's bit patterns -> FLAG in ws (recomputed every call)
//   - all params mirrored to bf16 in ws (flag-branched conversion kernels)
//   - VALU GEMM (BM=128,BN=64,BK=32, 8x4 reg tile), fused epilogues
//   - per-row-wave attention; rel-pos bias as per-query H+W dots
//   - final store branches on FLAG (fp32 float4 vs bf16 ushort4)
// ============================================================================

using u16 = unsigned short;
using u32 = unsigned int;

__device__ __forceinline__ float bfu2f(u16 u) { return __builtin_bit_cast(float, (u32)u << 16); }
__device__ __forceinline__ float bflo(u32 u)  { return __builtin_bit_cast(float, u << 16); }
__device__ __forceinline__ float bfhi(u32 u)  { return __builtin_bit_cast(float, u & 0xffff0000u); }
__device__ __forceinline__ u16   f2bfu(float f) {
  u32 u = __builtin_bit_cast(u32, f);
  return (u16)((u + 0x7fffu + ((u >> 16) & 1u)) >> 16);   // RNE
}

// ---------------------------------------------------------------------------
// dtype detector: even-indexed u16s of a bf16 tensor are plausible bf16
// (exp in [100,134] for ~N(0,1) data); of an fp32 tensor they are mantissa
// low-halves (uniform -> ~14% pass). FLAG=1 => bf16, FLAG=0 => fp32.
// ---------------------------------------------------------------------------
__global__ __launch_bounds__(256) void detect_k(const u16* __restrict__ x, int* __restrict__ flag)
{
  __shared__ int tot;
  if (threadIdx.x == 0) tot = 0;
  __syncthreads();
  int cnt = 0;
  for (int i = threadIdx.x; i < 4096; i += 256) {
    int e = (x[2 * i] >> 7) & 0xFF;
    cnt += (e >= 100 && e <= 134) ? 1 : 0;
  }
  atomicAdd(&tot, cnt);
  __syncthreads();
  if (threadIdx.x == 0) *flag = (tot >= 2458) ? 1 : 0;   // 60% of 4096
}

// ---------------------------------------------------------------------------
// Conversion kernels: src (fp32 or bf16 per flag) -> bf16 mirror in ws.
// ---------------------------------------------------------------------------
struct CvtEnt { const void* src; int n; int dstoff; };
struct CvtArgs { CvtEnt e[24]; int cnt; };

__global__ __launch_bounds__(256) void tobf_multi_k(CvtArgs a, u16* __restrict__ dst,
                                                    const int* __restrict__ flag)
{
  int gid = blockIdx.x * 256 + threadIdx.x;
  bool isbf = (*flag != 0);
  for (int t = 0; t < a.cnt; ++t) {
    if (gid < a.e[t].n) {
      u16 v = isbf ? ((const u16*)a.e[t].src)[gid]
                   : f2bfu(((const float*)a.e[t].src)[gid]);
      dst[a.e[t].dstoff + gid] = v;
    }
  }
}

__global__ __launch_bounds__(256) void tobf4_k(const void* __restrict__ src, u16* __restrict__ dst,
                                               int n4, const int* __restrict__ flag)
{
  int i = blockIdx.x * 256 + threadIdx.x;
  if (i >= n4) return;
  ushort4 o;
  if (*flag) {
    o = ((const ushort4*)src)[i];
  } else {
    float4 f = ((const float4*)src)[i];
    o.x = f2bfu(f.x); o.y = f2bfu(f.y); o.z = f2bfu(f.z); o.w = f2bfu(f.w);
  }
  ((ushort4*)dst)[i] = o;
}

// ---------------------------------------------------------------------------
// im2col for the 16x16/stride-16 patch embed: A[t][(ky*16+kx)*3+ci], bf16 out.
// ---------------------------------------------------------------------------
__global__ __launch_bounds__(256) void im2col_k(const void* __restrict__ xv, u16* __restrict__ a,
                                                const int* __restrict__ flag)
{
  int t = blockIdx.x, tid = threadIdx.x;          // t = py*64+px
  int py = t >> 6, px = t & 63;
  int ky = tid >> 4, kx = tid & 15;
  size_t src = (size_t)(py * 16 + ky) * 1024 + px * 16 + kx;
  u16 v0, v1, v2;
  if (*flag) {
    const u16* x = (const u16*)xv;
    v0 = x[src]; v1 = x[src + 1048576]; v2 = x[src + 2097152];
  } else {
    const float* x = (const float*)xv;
    v0 = f2bfu(x[src]); v1 = f2bfu(x[src + 1048576]); v2 = f2bfu(x[src + 2097152]);
  }
  size_t dst = (size_t)t * 768 + tid * 3;
  a[dst] = v0; a[dst + 1] = v1; a[dst + 2] = v2;
}

// ---------------------------------------------------------------------------
// LayerNorm over C=768, f32 in -> bf16 out.  var = E[x^2]-E[x]^2 (biased).
// g,b are bf16 mirrors.
// ---------------------------------------------------------------------------
__global__ __launch_bounds__(256) void ln_k(const float* __restrict__ x,
                                            const u16* __restrict__ g,
                                            const u16* __restrict__ b,
                                            u16* __restrict__ y)
{
  const int t = blockIdx.x, tid = threadIdx.x;
  const float* xp = x + (size_t)t * 768;
  float v0 = xp[tid], v1 = xp[tid + 256], v2 = xp[tid + 512];
  float s = v0 + v1 + v2;
  float q = v0 * v0 + v1 * v1 + v2 * v2;
  #pragma unroll
  for (int off = 32; off; off >>= 1) { s += __shfl_xor(s, off); q += __shfl_xor(q, off); }
  __shared__ float red[8];
  int wid = tid >> 6, lane = tid & 63;
  if (lane == 0) { red[wid] = s; red[4 + wid] = q; }
  __syncthreads();
  s = red[0] + red[1] + red[2] + red[3];
  q = red[4] + red[5] + red[6] + red[7];
  float mean = s * (1.f / 768.f);
  float var  = q * (1.f / 768.f) - mean * mean;
  float rstd = rsqrtf(var + 1e-5f);
  u16* yp = y + (size_t)t * 768;
  yp[tid]       = f2bfu((v0 - mean) * rstd * bfu2f(g[tid])       + bfu2f(b[tid]));
  yp[tid + 256] = f2bfu((v1 - mean) * rstd * bfu2f(g[tid + 256]) + bfu2f(b[tid + 256]));
  yp[tid + 512] = f2bfu((v2 - mean) * rstd * bfu2f(g[tid + 512]) + bfu2f(b[tid + 512]));
}

// ---------------------------------------------------------------------------
// Window partition 64x64 -> 25 windows of 14x14 (zero pad to 70x70), bf16.
// ---------------------------------------------------------------------------
__global__ __launch_bounds__(256) void win_part_k(const u16* __restrict__ ln, u16* __restrict__ w)
{
  int vid = blockIdx.x * 256 + threadIdx.x;       // vector-of-8 id
  if (vid >= 470400) return;                      // 4900*768/8
  size_t idx = (size_t)vid * 8;
  int c = (int)(idx % 768);
  int r = (int)(idx / 768);
  int win = r / 196, tok = r - win * 196;
  int gy = (win / 5) * 14 + tok / 14;
  int gx = (win % 5) * 14 + tok % 14;
  uint4 v = make_uint4(0, 0, 0, 0);
  if (gy < 64 && gx < 64)
    v = *(const uint4*)(ln + ((size_t)(gy * 64 + gx) * 768 + c));
  *(uint4*)(w + idx) = v;
}

// ---------------------------------------------------------------------------
// Tiled bf16 GEMM, fp32 accum: C = A(MxK) * B(KxN) + bias, fused epilogues.
// ---------------------------------------------------------------------------
#define BM 128
#define BN 64
#define BK 32
#define ASTR 136
#define BSTR 72

enum { MODE_FEAT = 0, MODE_QKV = 1, MODE_RES = 2, MODE_GELU = 3, MODE_OUT = 4 };

__global__ __launch_bounds__(256, 2) void gemm_k(
    const u16* __restrict__ A, const u16* __restrict__ B, const u16* __restrict__ bias,
    int M, int N, int K, int mode,
    float* __restrict__ outf, u16* __restrict__ outb,
    const float* __restrict__ res, const u16* __restrict__ pos,
    float* __restrict__ qf, u16* __restrict__ kb, u16* __restrict__ vb, int TW,
    const int* __restrict__ flagp)
{
  __shared__ u16 As[BK * ASTR];   // transposed: As[k][m]
  __shared__ u16 Bs[BK * BSTR];   // Bs[k][n]
  const int tid = threadIdx.x;
  const int m0 = blockIdx.y * BM, n0 = blockIdx.x * BN;
  const int tx = tid & 15, ty = tid >> 4;
  const int arow = tid >> 1, acol = (tid & 1) << 4;
  const int brow = tid >> 3, bcol = (tid & 7) << 3;
  float acc[8][4] = {};

  for (int k0 = 0; k0 < K; k0 += BK) {
    union { uint4 v[2]; u16 s[16]; } tmp;
    tmp.v[0] = make_uint4(0, 0, 0, 0); tmp.v[1] = tmp.v[0];
    int gm = m0 + arow;
    if (gm < M) {
      const uint4* ap = (const uint4*)(A + (size_t)gm * K + k0 + acol);
      tmp.v[0] = ap[0]; tmp.v[1] = ap[1];
    }
    uint4 bv = *(const uint4*)(B + (size_t)(k0 + brow) * N + n0 + bcol);
    __syncthreads();
    #pragma unroll
    for (int j = 0; j < 16; ++j) As[(acol + j) * ASTR + arow] = tmp.s[j];
    *(uint4*)&Bs[brow * BSTR + bcol] = bv;
    __syncthreads();
    #pragma unroll
    for (int kk = 0; kk < BK; ++kk) {
      ushort4 a0 = *(const ushort4*)&As[kk * ASTR + ty * 8];
      ushort4 a1 = *(const ushort4*)&As[kk * ASTR + ty * 8 + 4];
      ushort4 b0 = *(const ushort4*)&Bs[kk * BSTR + tx * 4];
      float af[8] = { bfu2f(a0.x), bfu2f(a0.y), bfu2f(a0.z), bfu2f(a0.w),
                      bfu2f(a1.x), bfu2f(a1.y), bfu2f(a1.z), bfu2f(a1.w) };
      float bf[4] = { bfu2f(b0.x), bfu2f(b0.y), bfu2f(b0.z), bfu2f(b0.w) };
      #pragma unroll
      for (int i = 0; i < 8; ++i)
        #pragma unroll
        for (int j = 0; j < 4; ++j) acc[i][j] += af[i] * bf[j];
    }
  }

  float bv4[4];
  #pragma unroll
  for (int j = 0; j < 4; ++j) bv4[j] = bfu2f(bias[n0 + tx * 4 + j]);

  if (mode == MODE_QKV) {
    const int s = n0 / 768, h = (n0 % 768) >> 6;
    #pragma unroll
    for (int i = 0; i < 8; ++i) {
      int gm = m0 + ty * 8 + i; if (gm >= M) break;
      int b = gm / TW, tok = gm - b * TW;
      size_t base = (((size_t)(b * 12 + h) * TW + tok) << 6) + tx * 4;
      float v0 = acc[i][0] + bv4[0], v1 = acc[i][1] + bv4[1];
      float v2 = acc[i][2] + bv4[2], v3 = acc[i][3] + bv4[3];
      if (s == 0) {
        *(float4*)(qf + base) = make_float4(v0, v1, v2, v3);
      } else {
        ushort4 u; u.x = f2bfu(v0); u.y = f2bfu(v1); u.z = f2bfu(v2); u.w = f2bfu(v3);
        *(ushort4*)((s == 1 ? kb : vb) + base) = u;
      }
    }
  } else {
    const bool outbf = (mode == MODE_OUT) ? (*flagp != 0) : false;
    #pragma unroll
    for (int i = 0; i < 8; ++i) {
      int gm = m0 + ty * 8 + i; if (gm >= M) break;
      size_t o = (size_t)gm * N + n0 + tx * 4;
      float v[4];
      #pragma unroll
      for (int j = 0; j < 4; ++j) v[j] = acc[i][j] + bv4[j];
      if (mode == MODE_FEAT) {
        ushort4 pz = *(const ushort4*)(pos + o);
        v[0] += bfu2f(pz.x); v[1] += bfu2f(pz.y); v[2] += bfu2f(pz.z); v[3] += bfu2f(pz.w);
        *(float4*)(outf + o) = make_float4(v[0], v[1], v[2], v[3]);
      } else if (mode == MODE_RES) {
        float4 r = *(const float4*)(res + o);
        *(float4*)(outf + o) = make_float4(v[0] + r.x, v[1] + r.y, v[2] + r.z, v[3] + r.w);
      } else if (mode == MODE_GELU) {
        ushort4 u;
        u.x = f2bfu(0.5f * v[0] * (1.f + erff(v[0] * 0.70710678f)));
        u.y = f2bfu(0.5f * v[1] * (1.f + erff(v[1] * 0.70710678f)));
        u.z = f2bfu(0.5f * v[2] * (1.f + erff(v[2] * 0.70710678f)));
        u.w = f2bfu(0.5f * v[3] * (1.f + erff(v[3] * 0.70710678f)));
        *(ushort4*)(outb + o) = u;
      } else { // MODE_OUT: final residual add; dtype per flag
        float4 r = *(const float4*)(res + o);
        float o0 = v[0] + r.x, o1 = v[1] + r.y, o2 = v[2] + r.z, o3 = v[3] + r.w;
        if (outbf) {
          ushort4 u; u.x = f2bfu(o0); u.y = f2bfu(o1); u.z = f2bfu(o2); u.w = f2bfu(o3);
          *(ushort4*)(outb + o) = u;
        } else {
          *(float4*)(outf + o) = make_float4(o0, o1, o2, o3);
        }
      }
    }
  }
}

// ---------------------------------------------------------------------------
// Attention, one wave per (batch*head, query) row.
//   score(j) = 0.125 * q.k_j + q.relh[qy-kh+TH-1] + q.relw[qx-kw+TD-1]
// ---------------------------------------------------------------------------
template<int N, int TH, int TD, bool WIN>
__global__ __launch_bounds__(256) void attn_k(
    const float* __restrict__ qf, const u16* __restrict__ kb, const u16* __restrict__ vb,
    const u16* __restrict__ relh, const u16* __restrict__ relw, u16* __restrict__ outb)
{
  constexpr int CH = (N + 63) / 64;
  constexpr int NP = CH * 64;
  __shared__ float biasH[4][TH];
  __shared__ float biasW[4][TD];
  __shared__ __align__(16) u16 ps[4][NP];
  const int wid = threadIdx.x >> 6, lane = threadIdx.x & 63;
  const int row = blockIdx.x * 4 + wid;           // row = bh*N + q
  const int bh = row / N, tq = row - bh * N;
  const int h = bh % 12, b = bh / 12;
  const int qy = tq / TD, qx = tq - qy * TD;

  float qreg[64];
  {
    const float4* qp = (const float4*)(qf + (((size_t)bh * N + tq) << 6));
    #pragma unroll
    for (int i = 0; i < 16; ++i) {
      float4 t = qp[i];
      qreg[i * 4] = t.x; qreg[i * 4 + 1] = t.y; qreg[i * 4 + 2] = t.z; qreg[i * 4 + 3] = t.w;
    }
  }
  if (lane < TH) {
    const uint4* rp = (const uint4*)(relh + ((size_t)(qy - lane + TH - 1) << 6));
    float d = 0.f;
    #pragma unroll
    for (int g2 = 0; g2 < 8; ++g2) {
      uint4 r = rp[g2];
      d += qreg[g2*8+0]*bflo(r.x) + qreg[g2*8+1]*bfhi(r.x)
         + qreg[g2*8+2]*bflo(r.y) + qreg[g2*8+3]*bfhi(r.y)
         + qreg[g2*8+4]*bflo(r.z) + qreg[g2*8+5]*bfhi(r.z)
         + qreg[g2*8+6]*bflo(r.w) + qreg[g2*8+7]*bfhi(r.w);
    }
    biasH[wid][lane] = d;
  }
  if (lane < TD) {
    const uint4* rp = (const uint4*)(relw + ((size_t)(qx - lane + TD - 1) << 6));
    float d = 0.f;
    #pragma unroll
    for (int g2 = 0; g2 < 8; ++g2) {
      uint4 r = rp[g2];
      d += qreg[g2*8+0]*bflo(r.x) + qreg[g2*8+1]*bfhi(r.x)
         + qreg[g2*8+2]*bflo(r.y) + qreg[g2*8+3]*bfhi(r.y)
         + qreg[g2*8+4]*bflo(r.z) + qreg[g2*8+5]*bfhi(r.z)
         + qreg[g2*8+6]*bflo(r.w) + qreg[g2*8+7]*bfhi(r.w);
    }
    biasW[wid][lane] = d;
  }
  __syncthreads();

  float smax = -3e38f;
  const u16* kbase = kb + ((size_t)bh * N << 6);
  for (int c = 0; c < CH; ++c) {
    int j = c * 64 + lane;
    float sc = -3e38f;
    if (j < N) {
      const uint4* kp = (const uint4*)(kbase + ((size_t)j << 6));
      float d = 0.f;
      #pragma unroll
      for (int g2 = 0; g2 < 8; ++g2) {
        uint4 r = kp[g2];
        d += qreg[g2*8+0]*bflo(r.x) + qreg[g2*8+1]*bfhi(r.x)
           + qreg[g2*8+2]*bflo(r.y) + qreg[g2*8+3]*bfhi(r.y)
           + qreg[g2*8+4]*bflo(r.z) + qreg[g2*8+5]*bfhi(r.z)
           + qreg[g2*8+6]*bflo(r.w) + qreg[g2*8+7]*bfhi(r.w);
      }
      int kh = j / TD, kw = j - kh * TD;
      sc = d * 0.125f + biasH[wid][kh] + biasW[wid][kw];
    }
    smax = fmaxf(smax, sc);
    ps[wid][c * 64 + lane] = f2bfu(sc);
  }
  #pragma unroll
  for (int off = 32; off; off >>= 1) smax = fmaxf(smax, __shfl_xor(smax, off));

  float lsum = 0.f;
  for (int c = 0; c < CH; ++c) {
    int j = c * 64 + lane;
    float sc = bfu2f(ps[wid][j]);
    float p = (j < N) ? __expf(sc - smax) : 0.f;
    lsum += p;
    ps[wid][j] = f2bfu(p);
  }
  #pragma unroll
  for (int off = 32; off; off >>= 1) lsum += __shfl_xor(lsum, off);
  const float linv = 1.f / lsum;
  __syncthreads();

  float accv = 0.f;
  const u16* vp = vb + ((size_t)bh * N << 6) + lane;
  constexpr int NF = N & ~7;
  for (int j0 = 0; j0 < NF; j0 += 8) {
    uint4 pw = *(const uint4*)&ps[wid][j0];
    accv += bflo(pw.x) * bfu2f(vp[(size_t)(j0 + 0) << 6]);
    accv += bfhi(pw.x) * bfu2f(vp[(size_t)(j0 + 1) << 6]);
    accv += bflo(pw.y) * bfu2f(vp[(size_t)(j0 + 2) << 6]);
    accv += bfhi(pw.y) * bfu2f(vp[(size_t)(j0 + 3) << 6]);
    accv += bflo(pw.z) * bfu2f(vp[(size_t)(j0 + 4) << 6]);
    accv += bfhi(pw.z) * bfu2f(vp[(size_t)(j0 + 5) << 6]);
    accv += bflo(pw.w) * bfu2f(vp[(size_t)(j0 + 6) << 6]);
    accv += bfhi(pw.w) * bfu2f(vp[(size_t)(j0 + 7) << 6]);
  }
  for (int j = NF; j < N; ++j) accv += bfu2f(ps[wid][j]) * bfu2f(vp[(size_t)j << 6]);
  accv *= linv;

  if (WIN) {
    int wy = b / 5, wx = b - wy * 5;
    int gy = wy * 14 + qy, gx = wx * 14 + qx;
    if (gy < 64 && gx < 64)
      outb[(size_t)(gy * 64 + gx) * 768 + h * 64 + lane] = f2bfu(accv);
  } else {
    outb[(size_t)tq * 768 + h * 64 + lane] = f2bfu(accv);
  }
}

// ---------------------------------------------------------------------------
extern "C" void kernel_launch(void* const* d_in, const int* in_sizes, int n_in,
                              void* d_out, int out_size, void* d_ws, size_t ws_size,
                              hipStream_t stream)
{
  const void* x      = d_in[0];
  const void* patchw = d_in[1];
  const void* patchb = d_in[2];
  const void* pos    = d_in[3];
  const void *ln1g1 = d_in[4],  *ln1b1 = d_in[5];
  const void *qkvw1 = d_in[6],  *qkvb1 = d_in[7];
  const void *projw1= d_in[8],  *projb1= d_in[9];
  const void *relh1 = d_in[10], *relw1 = d_in[11];
  const void *ln2g1 = d_in[12], *ln2b1 = d_in[13];
  const void *mw11  = d_in[14], *mb11  = d_in[15];
  const void *mw21  = d_in[16], *mb21  = d_in[17];
  const void *ln1g2 = d_in[18], *ln1b2 = d_in[19];
  const void *qkvw2 = d_in[20], *qkvb2 = d_in[21];
  const void *projw2= d_in[22], *projb2= d_in[23];
  const void *relh2 = d_in[24], *relw2 = d_in[25];
  const void *ln2g2 = d_in[26], *ln2b2 = d_in[27];
  const void *mw12  = d_in[28], *mb12  = d_in[29];
  const void *mw22  = d_in[30], *mb22  = d_in[31];

  char* w = (char*)d_ws;
  int*   FLAG = (int*)w;  w += 64;
  float* R0 = (float*)w;  w += 12582912;
  float* R1 = (float*)w;  w += 12582912;
  u16*   B0 = (u16*)w;    w += 6291456;
  u16*   Wb = (u16*)w;    w += 7526400;
  float* QF = (float*)w;  w += 15052800;
  u16*   KB = (u16*)w;    w += 7526400;
  u16*   VB = (u16*)w;    w += 7526400;
  u16*   Hb = (u16*)w;    w += 25165824;
  u16*   WA = (u16*)w;    w += 14155776;   // weight arena (bf16)
  u16*   POSb = (u16*)w;  w += 6291456;
  u16*   PRM = (u16*)w;   w += 106560;     // small params (bf16)
  u16*   Ap = Hb;                          // im2col matrix aliases MLP hidden

  // weight-arena element offsets
  constexpr int WA_QKV = 0, WA_PROJ = 1769472, WA_M1 = 2359296, WA_M2 = 4718592;
  // small-param element offsets
  constexpr int PRM_PATCHB = 0, PB1 = 768, PBLK = 26240, PB2 = 768 + PBLK;
  constexpr int O_QKVB = 0, O_PROJB = 2304, O_MB1 = 3072, O_MB2 = 6144,
                O_LN1G = 6912, O_LN1B = 7680, O_LN2G = 8448, O_LN2B = 9216,
                O_RELH = 9984, O_RELW = 18112;

  // ---- dtype detect + small-param conversion ----
  detect_k<<<1, 256, 0, stream>>>((const u16*)x, FLAG);
  CvtArgs ca; int kk = 0;
  auto add = [&](const void* s, int n, int off) { ca.e[kk].src = s; ca.e[kk].n = n; ca.e[kk].dstoff = off; ++kk; };
  add(patchb, 768, PRM_PATCHB);
  add(qkvb1, 2304, PB1 + O_QKVB); add(projb1, 768, PB1 + O_PROJB);
  add(mb11, 3072, PB1 + O_MB1);   add(mb21, 768, PB1 + O_MB2);
  add(ln1g1, 768, PB1 + O_LN1G);  add(ln1b1, 768, PB1 + O_LN1B);
  add(ln2g1, 768, PB1 + O_LN2G);  add(ln2b1, 768, PB1 + O_LN2B);
  add(relh1, 27 * 64, PB1 + O_RELH); add(relw1, 27 * 64, PB1 + O_RELW);
  add(qkvb2, 2304, PB2 + O_QKVB); add(projb2, 768, PB2 + O_PROJB);
  add(mb12, 3072, PB2 + O_MB1);   add(mb22, 768, PB2 + O_MB2);
  add(ln1g2, 768, PB2 + O_LN1G);  add(ln1b2, 768, PB2 + O_LN1B);
  add(ln2g2, 768, PB2 + O_LN2G);  add(ln2b2, 768, PB2 + O_LN2B);
  add(relh2, 127 * 64, PB2 + O_RELH); add(relw2, 127 * 64, PB2 + O_RELW);
  ca.cnt = kk;
  tobf_multi_k<<<32, 256, 0, stream>>>(ca, PRM, FLAG);
  tobf4_k<<<3072, 256, 0, stream>>>(pos, POSb, 786432, FLAG);

  // ---- patch embed ----
  tobf4_k<<<576, 256, 0, stream>>>(patchw, WA + WA_M1, 147456, FLAG);  // stage in mw1 slot
  im2col_k<<<4096, 256, 0, stream>>>(x, Ap, FLAG);
  gemm_k<<<dim3(12, 32), 256, 0, stream>>>(Ap, WA + WA_M1, PRM + PRM_PATCHB, 4096, 768, 768,
      MODE_FEAT, R0, nullptr, nullptr, POSb, nullptr, nullptr, nullptr, 0, FLAG);

  // ---- block 1 weights ----
  tobf4_k<<<1728, 256, 0, stream>>>(qkvw1, WA + WA_QKV, 442368, FLAG);
  tobf4_k<<<576,  256, 0, stream>>>(projw1, WA + WA_PROJ, 147456, FLAG);
  tobf4_k<<<2304, 256, 0, stream>>>(mw11, WA + WA_M1, 589824, FLAG);
  tobf4_k<<<2304, 256, 0, stream>>>(mw21, WA + WA_M2, 589824, FLAG);

  // ---- block 1 (windowed, ws=14) ----
  ln_k<<<4096, 256, 0, stream>>>(R0, PRM + PB1 + O_LN1G, PRM + PB1 + O_LN1B, B0);
  win_part_k<<<1838, 256, 0, stream>>>(B0, Wb);
  gemm_k<<<dim3(36, 39), 256, 0, stream>>>(Wb, WA + WA_QKV, PRM + PB1 + O_QKVB, 4900, 2304, 768,
      MODE_QKV, nullptr, nullptr, nullptr, nullptr, QF, KB, VB, 196, FLAG);
  attn_k<196, 14, 14, true><<<14700, 256, 0, stream>>>(QF, KB, VB,
      PRM + PB1 + O_RELH, PRM + PB1 + O_RELW, B0);
  gemm_k<<<dim3(12, 32), 256, 0, stream>>>(B0, WA + WA_PROJ, PRM + PB1 + O_PROJB, 4096, 768, 768,
      MODE_RES, R1, nullptr, R0, nullptr, nullptr, nullptr, nullptr, 0, FLAG);
  ln_k<<<4096, 256, 0, stream>>>(R1, PRM + PB1 + O_LN2G, PRM + PB1 + O_LN2B, B0);
  gemm_k<<<dim3(48, 32), 256, 0, stream>>>(B0, WA + WA_M1, PRM + PB1 + O_MB1, 4096, 3072, 768,
      MODE_GELU, nullptr, Hb, nullptr, nullptr, nullptr, nullptr, nullptr, 0, FLAG);
  gemm_k<<<dim3(12, 32), 256, 0, stream>>>(Hb, WA + WA_M2, PRM + PB1 + O_MB2, 4096, 768, 3072,
      MODE_RES, R0, nullptr, R1, nullptr, nullptr, nullptr, nullptr, 0, FLAG);

  // ---- block 2 weights ----
  tobf4_k<<<1728, 256, 0, stream>>>(qkvw2, WA + WA_QKV, 442368, FLAG);
  tobf4_k<<<576,  256, 0, stream>>>(projw2, WA + WA_PROJ, 147456, FLAG);
  tobf4_k<<<2304, 256, 0, stream>>>(mw12, WA + WA_M1, 589824, FLAG);
  tobf4_k<<<2304, 256, 0, stream>>>(mw22, WA + WA_M2, 589824, FLAG);

  // ---- block 2 (global) ----
  ln_k<<<4096, 256, 0, stream>>>(R0, PRM + PB2 + O_LN1G, PRM + PB2 + O_LN1B, B0);
  gemm_k<<<dim3(36, 32), 256, 0, stream>>>(B0, WA + WA_QKV, PRM + PB2 + O_QKVB, 4096, 2304, 768,
      MODE_QKV, nullptr, nullptr, nullptr, nullptr, QF, KB, VB, 4096, FLAG);
  attn_k<4096, 64, 64, false><<<12288, 256, 0, stream>>>(QF, KB, VB,
      PRM + PB2 + O_RELH, PRM + PB2 + O_RELW, B0);
  gemm_k<<<dim3(12, 32), 256, 0, stream>>>(B0, WA + WA_PROJ, PRM + PB2 + O_PROJB, 4096, 768, 768,
      MODE_RES, R1, nullptr, R0, nullptr, nullptr, nullptr, nullptr, 0, FLAG);
  ln_k<<<4096, 256, 0, stream>>>(R1, PRM + PB2 + O_LN2G, PRM + PB2 + O_LN2B, B0);
  gemm_k<<<dim3(48, 32), 256, 0, stream>>>(B0, WA + WA_M1, PRM + PB2 + O_MB1, 4096, 3072, 768,
      MODE_GELU, nullptr, Hb, nullptr, nullptr, nullptr, nullptr, nullptr, 0, FLAG);
  gemm_k<<<dim3(12, 32), 256, 0, stream>>>(Hb, WA + WA_M2, PRM + PB2 + O_MB2, 4096, 768, 3072,
      MODE_OUT, (float*)d_out, (u16*)d_out, R1, nullptr, nullptr, nullptr, nullptr, 0, FLAG);
}

// Round 3
// 1031.409 us; speedup vs baseline: 6.5660x; 6.5660x over previous
//
#include <hip/hip_runtime.h>

// ============================================================================
// ViT encoder (patch embed + windowed block + global block) on gfx950.
// Round 3: MFMA everywhere.
//   - mgemm_k: 128xBN tile (BN=64/128), BK=32, bf16 LDS staging, B fed as
//     B^T rows (weights pre-transposed by tobfT_k), mfma_f32_16x16x32_bf16,
//     fused epilogues (FEAT/QKV/RES/GELU/OUT). QKV epilogue writes Q,K as
//     [bh][tok][64] bf16 and V TRANSPOSED [bh][d][tok] for flash PV reads.
//   - flash_k: 64-query tile per block, online softmax, rel-pos bias via two
//     in-kernel MFMA GEMMs (Gh/Gw) against rel-table rows + Toeplitz gather.
//     P round-trips LDS (C-layout -> A-layout, m120-verified pattern).
//   - dtype-agnostic (runtime fp32-vs-bf16 flag) as round 2.
// MFMA layouts (m89/m91/m120 verified): A[m=lane&15][k=quad*8+j],
//   B^T rows as b-frag, C/D col=lane&15, row=quad*4+reg.
// ============================================================================

using u16 = unsigned short;
using u32 = unsigned int;
using short8  = __attribute__((ext_vector_type(8))) short;
using floatx4 = __attribute__((ext_vector_type(4))) float;

__device__ __forceinline__ float bfu2f(u16 u) { return __builtin_bit_cast(float, (u32)u << 16); }
__device__ __forceinline__ u16   f2bfu(float f) {
  u32 u = __builtin_bit_cast(u32, f);
  return (u16)((u + 0x7fffu + ((u >> 16) & 1u)) >> 16);   // RNE
}
#define DIV14(x) (((x) * 4682) >> 16)   // exact floor(x/14) for 0<=x<256

// ---------------------------------------------------------------------------
// dtype detector (round-2 proven): FLAG=1 => bf16 tensors, FLAG=0 => fp32.
// ---------------------------------------------------------------------------
__global__ __launch_bounds__(256) void detect_k(const u16* __restrict__ x, int* __restrict__ flag)
{
  __shared__ int tot;
  if (threadIdx.x == 0) tot = 0;
  __syncthreads();
  int cnt = 0;
  for (int i = threadIdx.x; i < 4096; i += 256) {
    int e = (x[2 * i] >> 7) & 0xFF;
    cnt += (e >= 100 && e <= 134) ? 1 : 0;
  }
  atomicAdd(&tot, cnt);
  __syncthreads();
  if (threadIdx.x == 0) *flag = (tot >= 2458) ? 1 : 0;
}

// ---------------------------------------------------------------------------
// small-param conversion (biases, ln, rel tables) -> bf16 mirror
// ---------------------------------------------------------------------------
struct CvtEnt { const void* src; int n; int dstoff; };
struct CvtArgs { CvtEnt e[24]; int cnt; };

__global__ __launch_bounds__(256) void tobf_multi_k(CvtArgs a, u16* __restrict__ dst,
                                                    const int* __restrict__ flag)
{
  int gid = blockIdx.x * 256 + threadIdx.x;
  bool isbf = (*flag != 0);
  for (int t = 0; t < a.cnt; ++t)
    if (gid < a.e[t].n)
      dst[a.e[t].dstoff + gid] = isbf ? ((const u16*)a.e[t].src)[gid]
                                      : f2bfu(((const float*)a.e[t].src)[gid]);
}

__global__ __launch_bounds__(256) void tobf4_k(const void* __restrict__ src, u16* __restrict__ dst,
                                               int n4, const int* __restrict__ flag)
{
  int i = blockIdx.x * 256 + threadIdx.x;
  if (i >= n4) return;
  ushort4 o;
  if (*flag) o = ((const ushort4*)src)[i];
  else {
    float4 f = ((const float4*)src)[i];
    o.x = f2bfu(f.x); o.y = f2bfu(f.y); o.z = f2bfu(f.z); o.w = f2bfu(f.w);
  }
  ((ushort4*)dst)[i] = o;
}

// ---------------------------------------------------------------------------
// Weight convert + transpose: W[K][N] (fp32/bf16) -> Wt[N][K] bf16.
// 64x64 tiles through LDS; K,N multiples of 64. grid(N/64, K/64).
// ---------------------------------------------------------------------------
__global__ __launch_bounds__(256) void tobfT_k(const void* __restrict__ src, u16* __restrict__ dst,
                                               int K, int N, const int* __restrict__ flag)
{
  __shared__ u16 t[64][65];
  const int n0 = blockIdx.x * 64, k0 = blockIdx.y * 64;
  const int r = threadIdx.x >> 2, c = (threadIdx.x & 3) * 16;
  if (*flag) {
    const u16* s = (const u16*)src + (size_t)(k0 + r) * N + n0 + c;
    union { uint4 v[2]; u16 e[16]; } u;
    u.v[0] = *(const uint4*)s; u.v[1] = *(const uint4*)(s + 8);
    #pragma unroll
    for (int j = 0; j < 16; ++j) t[c + j][r] = u.e[j];
  } else {
    const float* s = (const float*)src + (size_t)(k0 + r) * N + n0 + c;
    #pragma unroll
    for (int j = 0; j < 16; ++j) t[c + j][r] = f2bfu(s[j]);
  }
  __syncthreads();
  union { uint4 v[2]; u16 e[16]; } o;
  #pragma unroll
  for (int j = 0; j < 16; ++j) o.e[j] = t[r][c + j];
  u16* d = dst + (size_t)(n0 + r) * K + k0 + c;
  *(uint4*)d = o.v[0]; *(uint4*)(d + 8) = o.v[1];
}

// ---------------------------------------------------------------------------
// im2col for the 16x16/stride-16 patch embed (round-2 proven)
// ---------------------------------------------------------------------------
__global__ __launch_bounds__(256) void im2col_k(const void* __restrict__ xv, u16* __restrict__ a,
                                                const int* __restrict__ flag)
{
  int t = blockIdx.x, tid = threadIdx.x;
  int py = t >> 6, px = t & 63;
  int ky = tid >> 4, kx = tid & 15;
  size_t src = (size_t)(py * 16 + ky) * 1024 + px * 16 + kx;
  u16 v0, v1, v2;
  if (*flag) {
    const u16* x = (const u16*)xv;
    v0 = x[src]; v1 = x[src + 1048576]; v2 = x[src + 2097152];
  } else {
    const float* x = (const float*)xv;
    v0 = f2bfu(x[src]); v1 = f2bfu(x[src + 1048576]); v2 = f2bfu(x[src + 2097152]);
  }
  size_t dst = (size_t)t * 768 + tid * 3;
  a[dst] = v0; a[dst + 1] = v1; a[dst + 2] = v2;
}

// ---------------------------------------------------------------------------
// LayerNorm over C=768, f32 in -> bf16 out (round-2 proven)
// ---------------------------------------------------------------------------
__global__ __launch_bounds__(256) void ln_k(const float* __restrict__ x,
                                            const u16* __restrict__ g,
                                            const u16* __restrict__ b,
                                            u16* __restrict__ y)
{
  const int t = blockIdx.x, tid = threadIdx.x;
  const float* xp = x + (size_t)t * 768;
  float v0 = xp[tid], v1 = xp[tid + 256], v2 = xp[tid + 512];
  float s = v0 + v1 + v2;
  float q = v0 * v0 + v1 * v1 + v2 * v2;
  #pragma unroll
  for (int off = 32; off; off >>= 1) { s += __shfl_xor(s, off); q += __shfl_xor(q, off); }
  __shared__ float red[8];
  int wid = tid >> 6, lane = tid & 63;
  if (lane == 0) { red[wid] = s; red[4 + wid] = q; }
  __syncthreads();
  s = red[0] + red[1] + red[2] + red[3];
  q = red[4] + red[5] + red[6] + red[7];
  float mean = s * (1.f / 768.f);
  float var  = q * (1.f / 768.f) - mean * mean;
  float rstd = rsqrtf(var + 1e-5f);
  u16* yp = y + (size_t)t * 768;
  yp[tid]       = f2bfu((v0 - mean) * rstd * bfu2f(g[tid])       + bfu2f(b[tid]));
  yp[tid + 256] = f2bfu((v1 - mean) * rstd * bfu2f(g[tid + 256]) + bfu2f(b[tid + 256]));
  yp[tid + 512] = f2bfu((v2 - mean) * rstd * bfu2f(g[tid + 512]) + bfu2f(b[tid + 512]));
}

// ---------------------------------------------------------------------------
// Window partition 64x64 -> 25 windows of 14x14 zero-padded (round-2 proven)
// ---------------------------------------------------------------------------
__global__ __launch_bounds__(256) void win_part_k(const u16* __restrict__ ln, u16* __restrict__ w)
{
  int vid = blockIdx.x * 256 + threadIdx.x;
  if (vid >= 470400) return;
  size_t idx = (size_t)vid * 8;
  int c = (int)(idx % 768);
  int r = (int)(idx / 768);
  int win = r / 196, tok = r - win * 196;
  int gy = (win / 5) * 14 + tok / 14;
  int gx = (win % 5) * 14 + tok % 14;
  uint4 v = make_uint4(0, 0, 0, 0);
  if (gy < 64 && gx < 64)
    v = *(const uint4*)(ln + ((size_t)(gy * 64 + gx) * 768 + c));
  *(uint4*)(w + idx) = v;
}

// ---------------------------------------------------------------------------
// MFMA GEMM: C = A(MxK) * Bt(NxK)^T + bias, fused epilogues.
// 128xBN block tile, BK=32, 4 waves. BN=128: 2x2 waves of 64x64;
// BN=64: 4x1 waves of 32x64. Each 16x16 subtile = 1 mfma per BK step.
// ---------------------------------------------------------------------------
enum { MODE_FEAT = 0, MODE_QKV = 1, MODE_RES = 2, MODE_GELU = 3, MODE_OUT = 4 };

template<int BN>
__global__ __launch_bounds__(256) void mgemm_k(
    const u16* __restrict__ A, const u16* __restrict__ Bt, const u16* __restrict__ bias,
    int M, int N, int K, int mode,
    float* __restrict__ outf, u16* __restrict__ outb,
    const float* __restrict__ res, const u16* __restrict__ pos,
    u16* __restrict__ qb, u16* __restrict__ kb, u16* __restrict__ vt, int TW,
    const int* __restrict__ flagp)
{
  constexpr int NWN = BN / 64, NWM = 4 / NWN;
  constexpr int WTM = 128 / NWM;            // 64 or 32
  constexpr int MS = WTM / 16, NS = 4;
  __shared__ __align__(16) u16 As[128 * 32];
  __shared__ __align__(16) u16 Bs[BN * 32];
  const int tid = threadIdx.x;
  const int wid = tid >> 6, lane = tid & 63;
  const int l15 = lane & 15, quad = lane >> 4;
  const int wm = wid / NWN, wn = wid % NWN;
  const int m0 = blockIdx.y * 128, n0 = blockIdx.x * BN;

  floatx4 acc[MS][NS];
  #pragma unroll
  for (int i = 0; i < MS; ++i)
    #pragma unroll
    for (int j = 0; j < NS; ++j) acc[i][j] = (floatx4){0.f, 0.f, 0.f, 0.f};

  const int arow = tid >> 1, ak = (tid & 1) << 4;        // A: 128 rows x 2 chunks
  const int agr = min(m0 + arow, M - 1);
  const u16* aptr = A + (size_t)agr * K + ak;
  const u16* bptr;
  int brow, bk;
  if constexpr (BN == 128) { brow = tid >> 1; bk = (tid & 1) << 4; }
  else                     { brow = tid >> 2; bk = (tid & 3) << 3; }
  bptr = Bt + (size_t)(n0 + brow) * K + bk;

  for (int k0 = 0; k0 < K; k0 += 32) {
    uint4 av0 = *(const uint4*)(aptr + k0);
    uint4 av1 = *(const uint4*)(aptr + k0 + 8);
    uint4 bv0 = *(const uint4*)(bptr + k0);
    uint4 bv1;
    if constexpr (BN == 128) bv1 = *(const uint4*)(bptr + k0 + 8);
    __syncthreads();
    *(uint4*)&As[arow * 32 + ak]     = av0;
    *(uint4*)&As[arow * 32 + ak + 8] = av1;
    *(uint4*)&Bs[brow * 32 + bk] = bv0;
    if constexpr (BN == 128) *(uint4*)&Bs[brow * 32 + bk + 8] = bv1;
    __syncthreads();
    short8 af[MS], bf[NS];
    #pragma unroll
    for (int ms = 0; ms < MS; ++ms)
      af[ms] = *(const short8*)&As[(wm * WTM + ms * 16 + l15) * 32 + quad * 8];
    #pragma unroll
    for (int ns = 0; ns < NS; ++ns)
      bf[ns] = *(const short8*)&Bs[(wn * 64 + ns * 16 + l15) * 32 + quad * 8];
    #pragma unroll
    for (int ms = 0; ms < MS; ++ms)
      #pragma unroll
      for (int ns = 0; ns < NS; ++ns)
        acc[ms][ns] = __builtin_amdgcn_mfma_f32_16x16x32_bf16(af[ms], bf[ns], acc[ms][ns], 0, 0, 0);
  }

  const bool outbf = (mode == MODE_OUT) ? (*flagp != 0) : false;
  #pragma unroll
  for (int ms = 0; ms < MS; ++ms) {
    const int gmb = m0 + wm * WTM + ms * 16 + quad * 4;
    #pragma unroll
    for (int ns = 0; ns < NS; ++ns) {
      const int gn = n0 + wn * 64 + ns * 16 + l15;
      const float bb = bfu2f(bias[gn]);
      if (mode == MODE_QKV) {
        const int s = gn / 768, nn = gn - s * 768, h = nn >> 6, d = nn & 63;
        #pragma unroll
        for (int r = 0; r < 4; ++r) {
          int gm = gmb + r; if (gm >= M) continue;
          float v = acc[ms][ns][r] + bb;
          int b = gm / TW, tok = gm - b * TW;
          size_t bh = (size_t)(b * 12 + h);
          if (s == 0)      qb[(bh * TW + tok) * 64 + d] = f2bfu(v);
          else if (s == 1) kb[(bh * TW + tok) * 64 + d] = f2bfu(v);
          else             vt[(bh * 64 + d) * TW + tok] = f2bfu(v);
        }
      } else {
        #pragma unroll
        for (int r = 0; r < 4; ++r) {
          int gm = gmb + r; if (gm >= M) continue;
          size_t o = (size_t)gm * N + gn;
          float v = acc[ms][ns][r] + bb;
          if (mode == MODE_FEAT)      outf[o] = v + bfu2f(pos[o]);
          else if (mode == MODE_RES)  outf[o] = v + res[o];
          else if (mode == MODE_GELU) outb[o] = f2bfu(0.5f * v * (1.f + erff(v * 0.70710678f)));
          else {                      // MODE_OUT
            float ov = v + res[o];
            if (outbf) outb[o] = f2bfu(ov);
            else       outf[o] = ov;
          }
        }
      }
    }
  }
}

// ---------------------------------------------------------------------------
// MFMA flash attention. One block = one (bh, 64-query tile). 4 waves, each
// owns 16 q-rows. K/V tiles of 64 keys staged in LDS; V pre-transposed
// globally as [bh][d][tok]. Rel-pos bias: Gh/Gw computed by MFMA against
// rel-table rows, gathered Toeplitz-style in the S epilogue.
//   S = 0.125*(Q K^T) + Gh gather + Gw gather ; online softmax ; O += P V.
// ---------------------------------------------------------------------------
template<int NT, int TD, bool WIN>
__global__ __launch_bounds__(256) void flash_k(
    const u16* __restrict__ qb, const u16* __restrict__ kb, const u16* __restrict__ vt,
    const u16* __restrict__ relh, const u16* __restrict__ relw,
    u16* __restrict__ outb)
{
  constexpr int NTAB = 2 * TD - 1;
  constexpr int KT = (NT + 63) >> 6;
  constexpr int GHN = WIN ? 32 : 64;
  constexpr int GWN = WIN ? 32 : 128;
  constexpr int Q0 = 0, K0 = 4096, V0 = 8192, P0 = 12288, GH0 = 16384;
  constexpr int GW0 = GH0 + 64 * GHN, TOT = GW0 + 64 * GWN;
  constexpr int RB0 = K0;                       // rel staging aliases Ks
  __shared__ __align__(16) u16 lds[TOT];

  const int tid = threadIdx.x, wid = tid >> 6, lane = tid & 63;
  const int l15 = lane & 15, quad = lane >> 4;
  const int qt = blockIdx.x, bh = blockIdx.y;
  const int q0 = qt * 64;
  const size_t kvbase = (size_t)bh * NT * 64;
  const size_t vbase  = (size_t)bh * 64 * NT;

  // ---- stage Q tile (row-clamped) ----
  {
    const int r = tid >> 2, c = (tid & 3) << 4;
    const int tok = min(q0 + r, NT - 1);
    const uint4* p = (const uint4*)(qb + kvbase + (size_t)tok * 64 + c);
    *(uint4*)&lds[Q0 + r * 64 + c]     = p[0];
    *(uint4*)&lds[Q0 + r * 64 + c + 8] = p[1];
  }

  // ---- G phase: Gh / Gw via MFMA against rel-table rows ----
  auto stageRB = [&](const u16* tab, int rowoff, int maxrow) {
    const int r = tid >> 2, c = (tid & 3) << 4;
    const int tr = min(rowoff + r, maxrow);
    const uint4* p = (const uint4*)(tab + (size_t)tr * 64 + c);
    *(uint4*)&lds[RB0 + r * 64 + c]     = p[0];
    *(uint4*)&lds[RB0 + r * 64 + c + 8] = p[1];
  };
  auto gpass = [&](int ncols, int gbase, int gstride, int co) {
    for (int ns = 0; ns < ncols / 16; ++ns) {
      floatx4 g = (floatx4){0.f, 0.f, 0.f, 0.f};
      #pragma unroll
      for (int ks = 0; ks < 2; ++ks) {
        short8 a = *(const short8*)&lds[Q0 + (wid * 16 + l15) * 64 + ks * 32 + quad * 8];
        short8 b = *(const short8*)&lds[RB0 + (ns * 16 + l15) * 64 + ks * 32 + quad * 8];
        g = __builtin_amdgcn_mfma_f32_16x16x32_bf16(a, b, g, 0, 0, 0);
      }
      #pragma unroll
      for (int r = 0; r < 4; ++r)
        lds[gbase + (wid * 16 + quad * 4 + r) * gstride + co + ns * 16 + l15] = f2bfu(g[r]);
    }
  };

  stageRB(relh, WIN ? 0 : qt, NTAB - 1);
  __syncthreads();
  gpass(GHN, GH0, GHN, 0);
  __syncthreads();
  stageRB(relw, 0, NTAB - 1);
  __syncthreads();
  gpass(GWN > 64 ? 64 : GWN, GW0, GWN, 0);
  __syncthreads();
  if constexpr (GWN > 64) {
    stageRB(relw, 64, NTAB - 1);
    __syncthreads();
    gpass(64, GW0, GWN, 64);
    __syncthreads();
  }

  // ---- online-softmax state ----
  float mI[4], lI[4];
  floatx4 Oacc[4];
  #pragma unroll
  for (int r = 0; r < 4; ++r) { mI[r] = -3e38f; lI[r] = 0.f; }
  #pragma unroll
  for (int d = 0; d < 4; ++d) Oacc[d] = (floatx4){0.f, 0.f, 0.f, 0.f};

  // ---- K loop ----
  for (int kt = 0; kt < KT; ++kt) {
    __syncthreads();           // prior tile's LDS reads done before restage
    {
      const int r = tid >> 2, c = (tid & 3) << 4;
      const int key = min(kt * 64 + r, NT - 1);
      const uint4* p = (const uint4*)(kb + kvbase + (size_t)key * 64 + c);
      *(uint4*)&lds[K0 + r * 64 + c]     = p[0];
      *(uint4*)&lds[K0 + r * 64 + c + 8] = p[1];
    }
    if constexpr (NT % 64 == 0) {
      const int d = tid >> 2, c = (tid & 3) << 4;
      const uint4* p = (const uint4*)(vt + vbase + (size_t)d * NT + kt * 64 + c);
      *(uint4*)&lds[V0 + d * 64 + c]     = p[0];
      *(uint4*)&lds[V0 + d * 64 + c + 8] = p[1];
    } else {
      const int d = tid >> 2, c = (tid & 3) << 4;
      #pragma unroll
      for (int j = 0; j < 16; ++j) {
        int key = min(kt * 64 + c + j, NT - 1);
        lds[V0 + d * 64 + c + j] = vt[vbase + (size_t)d * NT + key];
      }
    }
    __syncthreads();

    // QK^T : wave's 16 q-rows x 64 keys
    floatx4 sacc[4];
    #pragma unroll
    for (int ns = 0; ns < 4; ++ns) sacc[ns] = (floatx4){0.f, 0.f, 0.f, 0.f};
    #pragma unroll
    for (int ks = 0; ks < 2; ++ks) {
      short8 a = *(const short8*)&lds[Q0 + (wid * 16 + l15) * 64 + ks * 32 + quad * 8];
      #pragma unroll
      for (int ns = 0; ns < 4; ++ns) {
        short8 b = *(const short8*)&lds[K0 + (ns * 16 + l15) * 64 + ks * 32 + quad * 8];
        sacc[ns] = __builtin_amdgcn_mfma_f32_16x16x32_bf16(a, b, sacc[ns], 0, 0, 0);
      }
    }

    // scale + rel bias + mask
    float sv[4][4];
    #pragma unroll
    for (int r = 0; r < 4; ++r) {
      const int tr = wid * 16 + quad * 4 + r;
      if constexpr (!WIN) {
        const float ghv = bfu2f(lds[GH0 + tr * 64 + (63 - kt)]);
        #pragma unroll
        for (int ns = 0; ns < 4; ++ns) {
          const int cj = ns * 16 + l15;
          sv[ns][r] = 0.125f * sacc[ns][r] + ghv + bfu2f(lds[GW0 + tr * 128 + (tr - cj + 63)]);
        }
      } else {
        const int tok = q0 + tr;
        const int qy = DIV14(tok), qx = tok - 14 * qy;
        #pragma unroll
        for (int ns = 0; ns < 4; ++ns) {
          const int j = kt * 64 + ns * 16 + l15;
          const int ky = DIV14(j), kx = j - 14 * ky;
          int ih = qy - ky + 13; ih = max(0, min(ih, GHN - 1));
          int iw = qx - kx + 13; iw = max(0, min(iw, GWN - 1));
          float s = 0.125f * sacc[ns][r] + bfu2f(lds[GH0 + tr * GHN + ih])
                                        + bfu2f(lds[GW0 + tr * GWN + iw]);
          sv[ns][r] = (j < NT) ? s : -1e30f;
        }
      }
    }

    // online softmax (rows live across the 16 lanes of a quad)
    #pragma unroll
    for (int r = 0; r < 4; ++r) {
      float rm = fmaxf(fmaxf(sv[0][r], sv[1][r]), fmaxf(sv[2][r], sv[3][r]));
      #pragma unroll
      for (int off = 1; off < 16; off <<= 1) rm = fmaxf(rm, __shfl_xor(rm, off));
      const float mn = fmaxf(mI[r], rm);
      const float al = __expf(mI[r] - mn);
      mI[r] = mn;
      float rs = 0.f;
      #pragma unroll
      for (int ns = 0; ns < 4; ++ns) {
        float p = __expf(sv[ns][r] - mn);
        rs += p;
        lds[P0 + wid * 1024 + (quad * 4 + r) * 64 + ns * 16 + l15] = f2bfu(p);
      }
      #pragma unroll
      for (int off = 1; off < 16; off <<= 1) rs += __shfl_xor(rs, off);
      lI[r] = lI[r] * al + rs;
      #pragma unroll
      for (int d = 0; d < 4; ++d) Oacc[d][r] *= al;
    }

    // PV : O[16 q][64 d] += P[16 q][64 key] * V[64 key][64 d]
    #pragma unroll
    for (int ks = 0; ks < 2; ++ks) {
      short8 a = *(const short8*)&lds[P0 + wid * 1024 + l15 * 64 + ks * 32 + quad * 8];
      #pragma unroll
      for (int d = 0; d < 4; ++d) {
        short8 b = *(const short8*)&lds[V0 + (d * 16 + l15) * 64 + ks * 32 + quad * 8];
        Oacc[d] = __builtin_amdgcn_mfma_f32_16x16x32_bf16(a, b, Oacc[d], 0, 0, 0);
      }
    }
  }

  // ---- output ----
  #pragma unroll
  for (int r = 0; r < 4; ++r) {
    const int tr = wid * 16 + quad * 4 + r;
    const float rinv = 1.f / lI[r];
    const int tok = q0 + tr;
    if constexpr (WIN) {
      if (tok >= NT) continue;
      const int win = bh / 12, h = bh - win * 12;
      const int ty = DIV14(tok), tx = tok - 14 * ty;
      const int gy = (win / 5) * 14 + ty, gx = (win % 5) * 14 + tx;
      if (gy >= 64 || gx >= 64) continue;
      u16* op = outb + (size_t)(gy * 64 + gx) * 768 + h * 64;
      #pragma unroll
      for (int d = 0; d < 4; ++d) op[d * 16 + l15] = f2bfu(Oacc[d][r] * rinv);
    } else {
      u16* op = outb + (size_t)tok * 768 + bh * 64;
      #pragma unroll
      for (int d = 0; d < 4; ++d) op[d * 16 + l15] = f2bfu(Oacc[d][r] * rinv);
    }
  }
}

// ---------------------------------------------------------------------------
extern "C" void kernel_launch(void* const* d_in, const int* in_sizes, int n_in,
                              void* d_out, int out_size, void* d_ws, size_t ws_size,
                              hipStream_t stream)
{
  const void* x      = d_in[0];
  const void* patchw = d_in[1];
  const void* patchb = d_in[2];
  const void* pos    = d_in[3];
  const void *ln1g1 = d_in[4],  *ln1b1 = d_in[5];
  const void *qkvw1 = d_in[6],  *qkvb1 = d_in[7];
  const void *projw1= d_in[8],  *projb1= d_in[9];
  const void *relh1 = d_in[10], *relw1 = d_in[11];
  const void *ln2g1 = d_in[12], *ln2b1 = d_in[13];
  const void *mw11  = d_in[14], *mb11  = d_in[15];
  const void *mw21  = d_in[16], *mb21  = d_in[17];
  const void *ln1g2 = d_in[18], *ln1b2 = d_in[19];
  const void *qkvw2 = d_in[20], *qkvb2 = d_in[21];
  const void *projw2= d_in[22], *projb2= d_in[23];
  const void *relh2 = d_in[24], *relw2 = d_in[25];
  const void *ln2g2 = d_in[26], *ln2b2 = d_in[27];
  const void *mw12  = d_in[28], *mb12  = d_in[29];
  const void *mw22  = d_in[30], *mb22  = d_in[31];

  char* w = (char*)d_ws;
  int*   FLAG = (int*)w;  w += 64;
  float* R0 = (float*)w;  w += 12582912;
  float* R1 = (float*)w;  w += 12582912;
  u16*   B0 = (u16*)w;    w += 6291456;
  u16*   Wb = (u16*)w;    w += 7526400;
  u16*   QB = (u16*)w;    w += 7526400;   // [bh][tok][64] bf16
  u16*   KB = (u16*)w;    w += 7526400;   // [bh][tok][64] bf16
  u16*   VT = (u16*)w;    w += 7526400;   // [bh][d][tok]  bf16 (transposed)
  u16*   Hb = (u16*)w;    w += 25165824;
  u16*   WA = (u16*)w;    w += 14155776;  // transposed weight arena (bf16)
  u16*   POSb = (u16*)w;  w += 6291456;
  u16*   PRM = (u16*)w;   w += 106560;
  u16*   Ap = Hb;                         // im2col matrix aliases MLP hidden

  constexpr int WA_QKV = 0, WA_PROJ = 1769472, WA_M1 = 2359296, WA_M2 = 4718592;
  constexpr int PRM_PATCHB = 0, PB1 = 768, PBLK = 26240, PB2 = 768 + PBLK;
  constexpr int O_QKVB = 0, O_PROJB = 2304, O_MB1 = 3072, O_MB2 = 6144,
                O_LN1G = 6912, O_LN1B = 7680, O_LN2G = 8448, O_LN2B = 9216,
                O_RELH = 9984, O_RELW = 18112;

  // ---- dtype detect + small-param conversion ----
  detect_k<<<1, 256, 0, stream>>>((const u16*)x, FLAG);
  CvtArgs ca; int kk = 0;
  auto add = [&](const void* s, int n, int off) { ca.e[kk].src = s; ca.e[kk].n = n; ca.e[kk].dstoff = off; ++kk; };
  add(patchb, 768, PRM_PATCHB);
  add(qkvb1, 2304, PB1 + O_QKVB); add(projb1, 768, PB1 + O_PROJB);
  add(mb11, 3072, PB1 + O_MB1);   add(mb21, 768, PB1 + O_MB2);
  add(ln1g1, 768, PB1 + O_LN1G);  add(ln1b1, 768, PB1 + O_LN1B);
  add(ln2g1, 768, PB1 + O_LN2G);  add(ln2b1, 768, PB1 + O_LN2B);
  add(relh1, 27 * 64, PB1 + O_RELH); add(relw1, 27 * 64, PB1 + O_RELW);
  add(qkvb2, 2304, PB2 + O_QKVB); add(projb2, 768, PB2 + O_PROJB);
  add(mb12, 3072, PB2 + O_MB1);   add(mb22, 768, PB2 + O_MB2);
  add(ln1g2, 768, PB2 + O_LN1G);  add(ln1b2, 768, PB2 + O_LN1B);
  add(ln2g2, 768, PB2 + O_LN2G);  add(ln2b2, 768, PB2 + O_LN2B);
  add(relh2, 127 * 64, PB2 + O_RELH); add(relw2, 127 * 64, PB2 + O_RELW);
  ca.cnt = kk;
  tobf_multi_k<<<32, 256, 0, stream>>>(ca, PRM, FLAG);
  tobf4_k<<<3072, 256, 0, stream>>>(pos, POSb, 786432, FLAG);

  // ---- patch embed ----
  tobfT_k<<<dim3(12, 12), 256, 0, stream>>>(patchw, WA + WA_M1, 768, 768, FLAG);
  im2col_k<<<4096, 256, 0, stream>>>(x, Ap, FLAG);
  mgemm_k<64><<<dim3(12, 32), 256, 0, stream>>>(Ap, WA + WA_M1, PRM + PRM_PATCHB,
      4096, 768, 768, MODE_FEAT, R0, nullptr, nullptr, POSb, nullptr, nullptr, nullptr, 0, FLAG);

  // ---- block 1 weights (transposed) ----
  tobfT_k<<<dim3(36, 12), 256, 0, stream>>>(qkvw1, WA + WA_QKV, 768, 2304, FLAG);
  tobfT_k<<<dim3(12, 12), 256, 0, stream>>>(projw1, WA + WA_PROJ, 768, 768, FLAG);
  tobfT_k<<<dim3(48, 12), 256, 0, stream>>>(mw11, WA + WA_M1, 768, 3072, FLAG);
  tobfT_k<<<dim3(12, 48), 256, 0, stream>>>(mw21, WA + WA_M2, 3072, 768, FLAG);

  // ---- block 1 (windowed, ws=14) ----
  ln_k<<<4096, 256, 0, stream>>>(R0, PRM + PB1 + O_LN1G, PRM + PB1 + O_LN1B, B0);
  win_part_k<<<1838, 256, 0, stream>>>(B0, Wb);
  mgemm_k<128><<<dim3(18, 39), 256, 0, stream>>>(Wb, WA + WA_QKV, PRM + PB1 + O_QKVB,
      4900, 2304, 768, MODE_QKV, nullptr, nullptr, nullptr, nullptr, QB, KB, VT, 196, FLAG);
  flash_k<196, 14, true><<<dim3(4, 300), 256, 0, stream>>>(QB, KB, VT,
      PRM + PB1 + O_RELH, PRM + PB1 + O_RELW, B0);
  mgemm_k<64><<<dim3(12, 32), 256, 0, stream>>>(B0, WA + WA_PROJ, PRM + PB1 + O_PROJB,
      4096, 768, 768, MODE_RES, R1, nullptr, R0, nullptr, nullptr, nullptr, nullptr, 0, FLAG);
  ln_k<<<4096, 256, 0, stream>>>(R1, PRM + PB1 + O_LN2G, PRM + PB1 + O_LN2B, B0);
  mgemm_k<128><<<dim3(24, 32), 256, 0, stream>>>(B0, WA + WA_M1, PRM + PB1 + O_MB1,
      4096, 3072, 768, MODE_GELU, nullptr, Hb, nullptr, nullptr, nullptr, nullptr, nullptr, 0, FLAG);
  mgemm_k<64><<<dim3(12, 32), 256, 0, stream>>>(Hb, WA + WA_M2, PRM + PB1 + O_MB2,
      4096, 768, 3072, MODE_RES, R0, nullptr, R1, nullptr, nullptr, nullptr, nullptr, 0, FLAG);

  // ---- block 2 weights (transposed) ----
  tobfT_k<<<dim3(36, 12), 256, 0, stream>>>(qkvw2, WA + WA_QKV, 768, 2304, FLAG);
  tobfT_k<<<dim3(12, 12), 256, 0, stream>>>(projw2, WA + WA_PROJ, 768, 768, FLAG);
  tobfT_k<<<dim3(48, 12), 256, 0, stream>>>(mw12, WA + WA_M1, 768, 3072, FLAG);
  tobfT_k<<<dim3(12, 48), 256, 0, stream>>>(mw22, WA + WA_M2, 3072, 768, FLAG);

  // ---- block 2 (global) ----
  ln_k<<<4096, 256, 0, stream>>>(R0, PRM + PB2 + O_LN1G, PRM + PB2 + O_LN1B, B0);
  mgemm_k<128><<<dim3(18, 32), 256, 0, stream>>>(B0, WA + WA_QKV, PRM + PB2 + O_QKVB,
      4096, 2304, 768, MODE_QKV, nullptr, nullptr, nullptr, nullptr, QB, KB, VT, 4096, FLAG);
  flash_k<4096, 64, false><<<dim3(64, 12), 256, 0, stream>>>(QB, KB, VT,
      PRM + PB2 + O_RELH, PRM + PB2 + O_RELW, B0);
  mgemm_k<64><<<dim3(12, 32), 256, 0, stream>>>(B0, WA + WA_PROJ, PRM + PB2 + O_PROJB,
      4096, 768, 768, MODE_RES, R1, nullptr, R0, nullptr, nullptr, nullptr, nullptr, 0, FLAG);
  ln_k<<<4096, 256, 0, stream>>>(R1, PRM + PB2 + O_LN2G, PRM + PB2 + O_LN2B, B0);
  mgemm_k<128><<<dim3(24, 32), 256, 0, stream>>>(B0, WA + WA_M1, PRM + PB2 + O_MB1,
      4096, 3072, 768, MODE_GELU, nullptr, Hb, nullptr, nullptr, nullptr, nullptr, nullptr, 0, FLAG);
  mgemm_k<64><<<dim3(12, 32), 256, 0, stream>>>(Hb, WA + WA_M2, PRM + PB2 + O_MB2,
      4096, 768, 3072, MODE_OUT, (float*)d_out, (u16*)d_out, R1, nullptr, nullptr, nullptr, nullptr, 0, FLAG);
}